// Round 5
// baseline (253.378 us; speedup 1.0000x reference)
//
#include <hip/hip_runtime.h>

// DIAGNOSTIC ROUND: R4 body executed TWICE per thread (identical second pass,
// same stores -> output unchanged, deterministic). Purpose: push this kernel's
// dispatch duration above the harness's 245us fillBuffer poisons so it appears
// in the rocprof top-5 and we finally see ITS counters.
//   FETCH_SIZE ~570 MB  -> Model A: nf gathers served by L3, HBM ~= mandatory;
//                          limiter is DRAM efficiency/latency, not traffic.
//   FETCH_SIZE >=1.0 GB -> Model B: gather re-fetches HBM; we're at the HBM
//                          ceiling and traffic reduction (bucketing) is the fix.
// The rep-dependent offset is multiplied by a runtime-zero argument so the
// compiler cannot CSE the two passes.

typedef float f4 __attribute__((ext_vector_type(4)));

__global__ __launch_bounds__(256) void equiv_mm_kernel(
    const float* __restrict__ basis,   // [E,4,4]
    const float* __restrict__ ew,      // [E,2,32]
    const float* __restrict__ nf,      // [N,4,32]
    const int*   __restrict__ U,       // [E]
    float*       __restrict__ out,     // [E,4,32]
    int E, int zero)                   // zero == 0 at runtime (opaque to compiler)
{
    int gid = blockIdx.x * blockDim.x + threadIdx.x;
    int e = gid >> 3;
    if (e >= E) return;
    int m0 = (gid & 7) << 2;   // channel offset: 0,4,...,28

    #pragma unroll 1
    for (int rep = 0; rep < 2; ++rep) {
        int eo = e + rep * zero;          // == e, but compiler can't prove it

        int u = U[eo];

        // gather source-node features (normal loads; the only reused data)
        const f4* xp = (const f4*)(nf + (size_t)u * 128 + m0);
        f4 x0 = xp[0];
        f4 x1 = xp[8];
        f4 x2 = xp[16];
        f4 x3 = xp[24];

        // per-edge 4x4 basis, single-use stream -> nontemporal
        const f4* bp = (const f4*)(basis + (size_t)eo * 16);
        f4 b0 = __builtin_nontemporal_load(bp + 0);
        f4 b1 = __builtin_nontemporal_load(bp + 1);
        f4 b2 = __builtin_nontemporal_load(bp + 2);
        f4 b3 = __builtin_nontemporal_load(bp + 3);

        // radial weights, single-use stream -> nontemporal
        const f4* wp = (const f4*)(ew + (size_t)eo * 64 + m0);
        f4 w0 = __builtin_nontemporal_load(wp + 0);
        f4 w1 = __builtin_nontemporal_load(wp + 8);

        // write-only output stream -> nontemporal
        f4* op = (f4*)(out + (size_t)eo * 128 + m0);
        __builtin_nontemporal_store((b0.x * x0 + b0.y * x1 + b0.z * x2 + b0.w * x3) * w0, op + 0);
        __builtin_nontemporal_store((b1.x * x0 + b1.y * x1 + b1.z * x2 + b1.w * x3) * w1, op + 8);
        __builtin_nontemporal_store((b2.x * x0 + b2.y * x1 + b2.z * x2 + b2.w * x3) * w1, op + 16);
        __builtin_nontemporal_store((b3.x * x0 + b3.y * x1 + b3.z * x2 + b3.w * x3) * w1, op + 24);
    }
}

extern "C" void kernel_launch(void* const* d_in, const int* in_sizes, int n_in,
                              void* d_out, int out_size, void* d_ws, size_t ws_size,
                              hipStream_t stream) {
    const float* basis = (const float*)d_in[0];   // [E,4,4]
    const float* ew    = (const float*)d_in[1];   // [E,2,32]
    const float* nf    = (const float*)d_in[2];   // [N,4,32]
    const int*   U     = (const int*)d_in[3];     // [E]
    float* out = (float*)d_out;

    int E = in_sizes[0] / 16;
    long long total = (long long)E * 8;           // 8 lanes per edge
    int block = 256;
    int grid = (int)((total + block - 1) / block);

    // runtime-zero, opaque to the compiler (in_sizes[0] is 12.8M, never 0)
    int zero = (in_sizes[0] == 0) ? 1 : 0;

    equiv_mm_kernel<<<grid, block, 0, stream>>>(basis, ew, nf, U, out, E, zero);
}